// Round 22
// baseline (107.281 us; speedup 1.0000x reference)
//
#include <hip/hip_runtime.h>
#include <hip/hip_bf16.h>
#include <math.h>

// Problem constants
#define HEADS    8
#define DIM_HEAD 64
#define QDIM     512
#define BATCH    4
#define NQ       1024
#define NKV      4096
#define NSPLIT   4
#define KEYS_PER_SPLIT (NKV / NSPLIT)   // 1024
#define NT (KEYS_PER_SPLIT / 64)        // 16 tiles per split

typedef float  f32x4  __attribute__((ext_vector_type(4)));
typedef float  f32x16 __attribute__((ext_vector_type(16)));
typedef __bf16 bf16x8 __attribute__((ext_vector_type(8)));
typedef __bf16 bf16x4 __attribute__((ext_vector_type(4)));

#define MFMA16(a, b, c) __builtin_amdgcn_mfma_f32_16x16x32_bf16((a), (b), (c), 0, 0, 0)
#define MFMA32(a, b, c) __builtin_amdgcn_mfma_f32_32x32x16_bf16((a), (b), (c), 0, 0, 0)

// Q-projection scale: (1/8) * log2(e)  [folds exp->exp2], softmax shift = -4
#define QSCALE 0.1803368801111204f
#define SSHIFT -4.0f

// fp32x8 -> bf16x8 (identical rounding to the old cvt_all pass)
__device__ __forceinline__ bf16x8 pack8(float4 lo, float4 hi) {
    bf16x8 o;
    o[0] = (__bf16)lo.x; o[1] = (__bf16)lo.y; o[2] = (__bf16)lo.z; o[3] = (__bf16)lo.w;
    o[4] = (__bf16)hi.x; o[5] = (__bf16)hi.y; o[6] = (__bf16)hi.z; o[7] = (__bf16)hi.w;
    return o;
}

// ---------------------------------------------------------------------------
// 128x128 GEMM tile body — REG-STAGED from FP32 sources (cvt fused into the
// staging path): per K-step each thread issues 8 float4 loads EARLY (2 A rows
// + 2 B rows, 8 floats each), computes the current LDS buffer (16 MFMA16),
// converts the staged fp32 to bf16 and ds_writes into the other buffer, ONE
// barrier. KV_OUT: K-half row-major ldc=512 / V-half transposed.
// ---------------------------------------------------------------------------
template <bool KV_OUT>
__device__ __forceinline__ void gemm128_rs(
    const float* __restrict__ A, const float* __restrict__ W,
    __bf16* __restrict__ Cb, __bf16* __restrict__ Vt,
    __bf16* As, __bf16* Bs,           // each 2 * 128*32 bf16 (double buffer)
    int bm, int bn, int K, int N, float scale)
{
    const int tid = threadIdx.x;
    const int l   = tid & 63;
    const int wv  = tid >> 6;
    const int wr  = wv >> 1, wc = wv & 1;
    const int l15 = l & 15, lg = l >> 4;

    // staging geometry: rows r0 and r0+64, col c0 (8 fp32 -> bf16x8)
    const int r0 = tid >> 2, c0 = (tid & 3) * 8;
    const float* ap = A + (size_t)(bm + r0) * K + c0;
    const float* wp = W + (size_t)(bn + r0) * K + c0;
    const size_t rowK64 = (size_t)64 * K;
    const int sidx0 = r0 * 32 + c0;            // LDS elem offset, row r0
    const int sidx1 = (r0 + 64) * 32 + c0;     // row r0+64
    const int BUF = 128 * 32;                  // elems per buffer

    const f32x4 zero = {0.f, 0.f, 0.f, 0.f};
    f32x4 acc[4][4];
#pragma unroll
    for (int i = 0; i < 4; ++i)
#pragma unroll
        for (int j = 0; j < 4; ++j)
            acc[i][j] = zero;

    const int nk = K / 32;

    // prologue: stage K-step 0 into buffer 0
    {
        float4 fa0 = *(const float4*)ap,            fa1 = *(const float4*)(ap + 4);
        float4 fa2 = *(const float4*)(ap + rowK64), fa3 = *(const float4*)(ap + rowK64 + 4);
        float4 fb0 = *(const float4*)wp,            fb1 = *(const float4*)(wp + 4);
        float4 fb2 = *(const float4*)(wp + rowK64), fb3 = *(const float4*)(wp + rowK64 + 4);
        ap += 32; wp += 32;
        *(bf16x8*)&As[sidx0] = pack8(fa0, fa1);
        *(bf16x8*)&As[sidx1] = pack8(fa2, fa3);
        *(bf16x8*)&Bs[sidx0] = pack8(fb0, fb1);
        *(bf16x8*)&Bs[sidx1] = pack8(fb2, fb3);
    }
    __syncthreads();

    int cur = 0;
    for (int t = 0; t < nk - 1; ++t) {
        // issue next K-step's loads (latency hides under the MFMAs below)
        float4 fa0 = *(const float4*)ap,            fa1 = *(const float4*)(ap + 4);
        float4 fa2 = *(const float4*)(ap + rowK64), fa3 = *(const float4*)(ap + rowK64 + 4);
        float4 fb0 = *(const float4*)wp,            fb1 = *(const float4*)(wp + 4);
        float4 fb2 = *(const float4*)(wp + rowK64), fb3 = *(const float4*)(wp + rowK64 + 4);
        ap += 32; wp += 32;

        {   // compute from buf[cur]
            bf16x8 af[4], bfr[4];
#pragma unroll
            for (int i = 0; i < 4; ++i) {
                af[i]  = *(const bf16x8*)&As[cur * BUF + (wr * 64 + i * 16 + l15) * 32 + lg * 8];
                bfr[i] = *(const bf16x8*)&Bs[cur * BUF + (wc * 64 + i * 16 + l15) * 32 + lg * 8];
            }
#pragma unroll
            for (int i = 0; i < 4; ++i)
#pragma unroll
                for (int j = 0; j < 4; ++j)
                    acc[i][j] = MFMA16(af[i], bfr[j], acc[i][j]);
        }

        // convert + write next K-step into the other buffer
        int nb = (cur ^ 1) * BUF;
        *(bf16x8*)&As[nb + sidx0] = pack8(fa0, fa1);
        *(bf16x8*)&As[nb + sidx1] = pack8(fa2, fa3);
        *(bf16x8*)&Bs[nb + sidx0] = pack8(fb0, fb1);
        *(bf16x8*)&Bs[nb + sidx1] = pack8(fb2, fb3);
        __syncthreads();
        cur ^= 1;
    }
    {   // final K-step
        bf16x8 af[4], bfr[4];
#pragma unroll
        for (int i = 0; i < 4; ++i) {
            af[i]  = *(const bf16x8*)&As[cur * BUF + (wr * 64 + i * 16 + l15) * 32 + lg * 8];
            bfr[i] = *(const bf16x8*)&Bs[cur * BUF + (wc * 64 + i * 16 + l15) * 32 + lg * 8];
        }
#pragma unroll
        for (int i = 0; i < 4; ++i)
#pragma unroll
            for (int j = 0; j < 4; ++j)
                acc[i][j] = MFMA16(af[i], bfr[j], acc[i][j]);
    }

    if (KV_OUT) {
        if (bn < QDIM) {
            // K half: row-major, ldc = QDIM (K-only buffer)
#pragma unroll
            for (int i = 0; i < 4; ++i) {
                int row0 = bm + wr * 64 + i * 16 + lg * 4;
#pragma unroll
                for (int j = 0; j < 4; ++j) {
                    int col = bn + wc * 64 + j * 16 + l15;
#pragma unroll
                    for (int r = 0; r < 4; ++r)
                        Cb[(size_t)(row0 + r) * QDIM + col] = (__bf16)(acc[i][j][r] * scale);
                }
            }
        } else {
            // V half: transposed store Vt[(b*H+h)*64+d][t..t+3]
#pragma unroll
            for (int i = 0; i < 4; ++i) {
                int row0 = bm + wr * 64 + i * 16 + lg * 4;   // global token row
                int bb = row0 >> 12;
                int tt = row0 & (NKV - 1);
#pragma unroll
                for (int j = 0; j < 4; ++j) {
                    int vcol = bn + wc * 64 + j * 16 + l15 - QDIM;
                    int hh = vcol >> 6, dd = vcol & 63;
                    bf16x4 o4;
#pragma unroll
                    for (int r = 0; r < 4; ++r) o4[r] = (__bf16)(acc[i][j][r] * scale);
                    *(bf16x4*)&Vt[((size_t)(bb * HEADS + hh) * DIM_HEAD + dd) * NKV + tt] = o4;
                }
            }
        }
    } else {
#pragma unroll
        for (int i = 0; i < 4; ++i) {
            int row0 = bm + wr * 64 + i * 16 + lg * 4;
#pragma unroll
            for (int j = 0; j < 4; ++j) {
                int col = bn + wc * 64 + j * 16 + l15;
#pragma unroll
                for (int r = 0; r < 4; ++r)
                    Cb[(size_t)(row0 + r) * N + col] = (__bf16)(acc[i][j][r] * scale);
            }
        }
    }
}

// ---------------------------------------------------------------------------
// Fused projections (fp32 inputs, cvt fused): XCD-chunked swizzle
// (1152 = 8 x 144): work = (bid%8)*144 + bid/8. kv works 0..1023; q works
// 1024..1151. Reg-staged fp32->bf16 body.
// ---------------------------------------------------------------------------
__global__ __launch_bounds__(256, 2) void proj_fused(
    const float* __restrict__ x,   const float* __restrict__ Wq,
    __bf16* __restrict__ qbuf,
    const float* __restrict__ ctx, const float* __restrict__ Wkv,
    __bf16* __restrict__ kvbK, __bf16* __restrict__ vtb)
{
    __shared__ __bf16 As[2 * 128 * 32];
    __shared__ __bf16 Bs[2 * 128 * 32];

    const int bid = (blockIdx.x & 7) * 144 + (blockIdx.x >> 3);   // bijective
    if (bid < 1024) {
        int bn = (bid & 7) * 128;
        int bm = (bid >> 3) * 128;
        gemm128_rs<true>(ctx, Wkv, kvbK, vtb, As, Bs, bm, bn, QDIM, 2 * QDIM, 1.0f);
    } else {
        int q  = bid - 1024;           // 0..127
        int bn = (q & 3) * 128;
        int bm = (q >> 2) * 128;
        gemm128_rs<false>(x, Wq, qbuf, nullptr, As, Bs, bm, bn, QDIM, QDIM, QSCALE);
    }
}

// ---------------------------------------------------------------------------
// bf16 MFMA GEMM, 128x64 tile, reg-staged dbuf — final projection (N=512).
// A = aob (bf16, internal); W = Wo (fp32, converted in-register). 1-D grid of
// 256 blocks with XCD-chunked swizzle (256 = 8 x 32).
// ---------------------------------------------------------------------------
__global__ __launch_bounds__(256, 2) void gemm_bt_64f(
    const __bf16* __restrict__ A, const float* __restrict__ W,
    const float* __restrict__ bias, float* __restrict__ Cf,
    int M, int N, int K)
{
    __shared__ __bf16 As[2 * 128 * 32];
    __shared__ __bf16 Bs[2 * 64 * 32];

    const int tid = threadIdx.x;
    const int l   = tid & 63;
    const int wv  = tid >> 6;
    const int wr  = wv >> 1, wc = wv & 1;
    const int l15 = l & 15, lg = l >> 4;
    const int bid = (blockIdx.x & 7) * 32 + (blockIdx.x >> 3);    // bijective
    const int bm  = (bid >> 3) * 128, bn = (bid & 7) * 64;

    const int r0 = tid >> 2, c0 = (tid & 3) * 8;
    const __bf16* ap = A + (size_t)(bm + r0) * K + c0;
    const float*  wp = W + (size_t)(bn + r0) * K + c0;   // rows 0..63 only
    const size_t rowK64 = (size_t)64 * K;
    const int sidx0 = r0 * 32 + c0;
    const int sidx1 = (r0 + 64) * 32 + c0;
    const int ABUF = 128 * 32, BBUF = 64 * 32;
    const bool bact = r0 < 64;                            // threads staging B

    const f32x4 zero = {0.f, 0.f, 0.f, 0.f};
    f32x4 acc[4][2];
#pragma unroll
    for (int i = 0; i < 4; ++i)
#pragma unroll
        for (int j = 0; j < 2; ++j)
            acc[i][j] = zero;

    const int nk = K / 32;

    {   // prologue
        bf16x8 a0 = *(const bf16x8*)ap;
        bf16x8 a1 = *(const bf16x8*)(ap + rowK64);
        float4 fb0, fb1;
        if (bact) { fb0 = *(const float4*)wp; fb1 = *(const float4*)(wp + 4); }
        ap += 32; wp += 32;
        *(bf16x8*)&As[sidx0] = a0;
        *(bf16x8*)&As[sidx1] = a1;
        if (bact) *(bf16x8*)&Bs[sidx0] = pack8(fb0, fb1);
    }
    __syncthreads();

    int cur = 0;
    for (int t = 0; t < nk - 1; ++t) {
        bf16x8 a0 = *(const bf16x8*)ap;
        bf16x8 a1 = *(const bf16x8*)(ap + rowK64);
        float4 fb0, fb1;
        if (bact) { fb0 = *(const float4*)wp; fb1 = *(const float4*)(wp + 4); }
        ap += 32; wp += 32;

        {
            bf16x8 af[4], bfr[2];
#pragma unroll
            for (int i = 0; i < 4; ++i)
                af[i]  = *(const bf16x8*)&As[cur * ABUF + (wr * 64 + i * 16 + l15) * 32 + lg * 8];
#pragma unroll
            for (int j = 0; j < 2; ++j)
                bfr[j] = *(const bf16x8*)&Bs[cur * BBUF + (wc * 32 + j * 16 + l15) * 32 + lg * 8];
#pragma unroll
            for (int i = 0; i < 4; ++i)
#pragma unroll
                for (int j = 0; j < 2; ++j)
                    acc[i][j] = MFMA16(af[i], bfr[j], acc[i][j]);
        }

        *(bf16x8*)&As[(cur ^ 1) * ABUF + sidx0] = a0;
        *(bf16x8*)&As[(cur ^ 1) * ABUF + sidx1] = a1;
        if (bact) *(bf16x8*)&Bs[(cur ^ 1) * BBUF + sidx0] = pack8(fb0, fb1);
        __syncthreads();
        cur ^= 1;
    }
    {
        bf16x8 af[4], bfr[2];
#pragma unroll
        for (int i = 0; i < 4; ++i)
            af[i]  = *(const bf16x8*)&As[cur * ABUF + (wr * 64 + i * 16 + l15) * 32 + lg * 8];
#pragma unroll
        for (int j = 0; j < 2; ++j)
            bfr[j] = *(const bf16x8*)&Bs[cur * BBUF + (wc * 32 + j * 16 + l15) * 32 + lg * 8];
#pragma unroll
        for (int i = 0; i < 4; ++i)
#pragma unroll
            for (int j = 0; j < 2; ++j)
                acc[i][j] = MFMA16(af[i], bfr[j], acc[i][j]);
    }

#pragma unroll
    for (int i = 0; i < 4; ++i) {
        int row0 = bm + wr * 64 + i * 16 + lg * 4;
#pragma unroll
        for (int j = 0; j < 2; ++j) {
            int col = bn + wc * 32 + j * 16 + l15;
            float bv = bias[col];
#pragma unroll
            for (int r = 0; r < 4; ++r)
                Cf[(size_t)(row0 + r) * N + col] = acc[i][j][r] + bv;
        }
    }
}

// ---------------------------------------------------------------------------
// Flash attention, 32x32x16 MFMA, swapped operands, K-split x4, static-shift
// softmax. r12-proven kernel (45.0 µs): KVBLK=64, 512-thread blocks (8 waves,
// 256 q-rows), double-buffered LDS, ONE barrier per tile, early-issue loads,
// shiftv C-operand, VALU lsum. 1-D XCD grid: bid%8 = h. UNCHANGED.
// ---------------------------------------------------------------------------
#define LSA 72

__device__ inline unsigned pkbf(float a, float b) {
    union { __bf16 h[2]; unsigned u; } r;
    r.h[0] = (__bf16)a; r.h[1] = (__bf16)b;
    return r.u;
}

__global__ __launch_bounds__(512, 4) void attn_mfma32(
    const __bf16* __restrict__ Q,      // [B*NQ, 512], pre-scaled by QSCALE
    const __bf16* __restrict__ Kb,     // [B*NKV, 512] K-only row-major
    const __bf16* __restrict__ VtG,    // [(B*H)*64][NKV] transposed V
    __bf16* __restrict__ OpartT,       // [NSPLIT*B*H][64 d][1024 q] bf16
    float* __restrict__ lbuf)          // [NSPLIT*B*H*NQ] f32 partial denoms
{
    __shared__ __bf16 Ks[2][64][LSA];
    __shared__ __bf16 Vs[2][64][LSA];  // Vs[buf][d][key]

    const int tid = threadIdx.x;
    const int w   = tid >> 6;          // 0..7
    const int l   = tid & 63;
    const int l31 = l & 31;
    const int hl  = l >> 5;

    // 1-D grid decomposition: bid = qbi*128 + (zz*8 + h); 512 blocks total
    const int bid   = blockIdx.x;
    const int inner = bid & 127;
    const int qbi   = bid >> 7;        // 0..3
    const int zz    = inner >> 3;      // 0..15
    const int h     = inner & 7;
    const int b     = zz & 3;
    const int split = zz >> 2;
    const int qb    = qbi * 256;       // 256 q-rows per block
    const int k_begin = split * KEYS_PER_SPLIT;

    // register constant: softmax shift as MFMA C-operand
    f32x16 shiftv;
#pragma unroll
    for (int r = 0; r < 16; ++r) shiftv[r] = SSHIFT;

    // Q fragments hoisted to registers
    const int qrow = qb + w * 32 + l31;
    const __bf16* qptr = Q + (size_t)(b * NQ + qrow) * QDIM + h * DIM_HEAD + hl * 8;
    bf16x8 qa[4];
#pragma unroll
    for (int m = 0; m < 4; ++m) qa[m] = *(const bf16x8*)(qptr + m * 16);

    // staging pointers: one bf16x8 of K and one of V per thread per tile
    const size_t kstep = (size_t)64 * QDIM;
    const int key0 = tid >> 3, ch = (tid & 7) * 8;       // K[key0][ch..ch+7]
    const __bf16* kp = Kb + (size_t)(b * NKV + k_begin + key0) * QDIM + h * DIM_HEAD + ch;
    const int vd = tid >> 3, vch = (tid & 7) * 8;        // Vt[vd][vch..vch+7]
    const __bf16* vp = VtG + ((size_t)(b * HEADS + h) * DIM_HEAD + vd) * NKV + k_begin + vch;

    f32x16 o0, o1;
#pragma unroll
    for (int r = 0; r < 16; ++r) { o0[r] = 0.f; o1[r] = 0.f; }
    float lsum = 0.0f;

    // per-tile compute from buffer `cur`
    auto compute_tile = [&](int cur) {
        f32x16 sf0, sf1;
        {
            bf16x8 kf0 = *(const bf16x8*)&Ks[cur][l31][hl * 8];
            bf16x8 kf1 = *(const bf16x8*)&Ks[cur][32 + l31][hl * 8];
            sf0 = MFMA32(kf0, qa[0], shiftv);
            sf1 = MFMA32(kf1, qa[0], shiftv);
        }
#pragma unroll
        for (int m = 1; m < 4; ++m) {
            bf16x8 kf0 = *(const bf16x8*)&Ks[cur][l31][m * 16 + hl * 8];
            bf16x8 kf1 = *(const bf16x8*)&Ks[cur][32 + l31][m * 16 + hl * 8];
            sf0 = MFMA32(kf0, qa[m], sf0);
            sf1 = MFMA32(kf1, qa[m], sf1);
        }

        unsigned pk0[8], pk1[8];
#pragma unroll
        for (int i = 0; i < 8; ++i) {
            float a0 = __builtin_amdgcn_exp2f(sf0[2 * i]);
            float a1 = __builtin_amdgcn_exp2f(sf0[2 * i + 1]);
            float b0 = __builtin_amdgcn_exp2f(sf1[2 * i]);
            float b1 = __builtin_amdgcn_exp2f(sf1[2 * i + 1]);
            lsum += (a0 + a1) + (b0 + b1);
            pk0[i] = pkbf(a0, a1);
            pk1[i] = pkbf(b0, b1);
        }

        // half-exchange via permlane32_swap: X.hi <-> Y.lo
        asm volatile("v_permlane32_swap_b32 %0, %1" : "+v"(pk0[0]), "+v"(pk0[2]));
        asm volatile("v_permlane32_swap_b32 %0, %1" : "+v"(pk0[1]), "+v"(pk0[3]));
        asm volatile("v_permlane32_swap_b32 %0, %1" : "+v"(pk0[4]), "+v"(pk0[6]));
        asm volatile("v_permlane32_swap_b32 %0, %1" : "+v"(pk0[5]), "+v"(pk0[7]));
        asm volatile("v_permlane32_swap_b32 %0, %1" : "+v"(pk1[0]), "+v"(pk1[2]));
        asm volatile("v_permlane32_swap_b32 %0, %1" : "+v"(pk1[1]), "+v"(pk1[3]));
        asm volatile("v_permlane32_swap_b32 %0, %1" : "+v"(pk1[4]), "+v"(pk1[6]));
        asm volatile("v_permlane32_swap_b32 %0, %1" : "+v"(pk1[5]), "+v"(pk1[7]));

        union { unsigned u[4]; bf16x8 v; } F0, F1, F2, F3;
        F0.u[0] = pk0[0]; F0.u[1] = pk0[1]; F0.u[2] = pk0[2]; F0.u[3] = pk0[3];
        F1.u[0] = pk0[4]; F1.u[1] = pk0[5]; F1.u[2] = pk0[6]; F1.u[3] = pk0[7];
        F2.u[0] = pk1[0]; F2.u[1] = pk1[1]; F2.u[2] = pk1[2]; F2.u[3] = pk1[3];
        F3.u[0] = pk1[4]; F3.u[1] = pk1[5]; F3.u[2] = pk1[6]; F3.u[3] = pk1[7];
        bf16x8 pf[4] = { F0.v, F1.v, F2.v, F3.v };

#pragma unroll
        for (int f = 0; f < 4; ++f) {
            bf16x8 v0 = *(const bf16x8*)&Vs[cur][l31][f * 16 + hl * 8];
            bf16x8 v1 = *(const bf16x8*)&Vs[cur][32 + l31][f * 16 + hl * 8];
            o0 = MFMA32(v0, pf[f], o0);
            o1 = MFMA32(v1, pf[f], o1);
        }
    };

    // prologue: stage tile 0
    {
        bf16x8 kr = *(const bf16x8*)kp;
        bf16x8 vr = *(const bf16x8*)vp;
        kp += kstep; vp += 64;
        *(bf16x8*)&Ks[0][key0][ch] = kr;
        *(bf16x8*)&Vs[0][vd][vch]  = vr;
    }
    __syncthreads();

    int cur = 0;
    for (int t = 0; t < NT - 1; ++t) {
        // issue next tile's loads (latency hidden under compute below)
        bf16x8 kr = *(const bf16x8*)kp;
        bf16x8 vr = *(const bf16x8*)vp;
        kp += kstep; vp += 64;

        compute_tile(cur);

        // write next tile into the other buffer (no pre-write barrier needed)
        *(bf16x8*)&Ks[cur ^ 1][key0][ch] = kr;
        *(bf16x8*)&Vs[cur ^ 1][vd][vch]  = vr;
        __syncthreads();
        cur ^= 1;
    }
    compute_tile(cur);

    // ---- epilogue ----
    float ltot = lsum + __shfl_xor(lsum, 32);
    const int S1 = BATCH * HEADS * NQ;
    int qidx = (b * HEADS + h) * NQ + qrow;
    if (l < 32) lbuf[(size_t)split * S1 + qidx] = ltot;

    __bf16* plane = OpartT + (size_t)(split * BATCH * HEADS + b * HEADS + h) * DIM_HEAD * NQ;
#pragma unroll
    for (int r = 0; r < 16; ++r) {
        int d = (r & 3) + 8 * (r >> 2) + 4 * hl;
        plane[(size_t)d * NQ + qrow]        = (__bf16)o0[r];
        plane[(size_t)(32 + d) * NQ + qrow] = (__bf16)o1[r];
    }
}

// ---------------------------------------------------------------------------
// Combine: out[q,d] = (sum_s O_s[d,q]) / (sum_s l_s[q]).
// ---------------------------------------------------------------------------
__global__ __launch_bounds__(256) void attn_combine(
    const __bf16* __restrict__ OpartT, const float* __restrict__ lbuf,
    __bf16* __restrict__ aob)
{
    __shared__ float T[64][65];
    __shared__ float INV[64];

    const int tid = threadIdx.x;
    const int q0  = blockIdx.x * 64;
    const int h   = blockIdx.y;
    const int b   = blockIdx.z;
    const int S1  = BATCH * HEADS * NQ;

    if (tid < 64) {
        int qidx = (b * HEADS + h) * NQ + q0 + tid;
        float den = 0.f;
#pragma unroll
        for (int s = 0; s < NSPLIT; ++s) den += lbuf[(size_t)s * S1 + qidx];
        INV[tid] = 1.0f / den;
    }
    __syncthreads();

    const int qq = (tid & 15) * 4;
    const int dr = tid >> 4;
#pragma unroll
    for (int dd = 0; dd < 4; ++dd) {
        int d = dr + dd * 16;
        f32x4 acc = {0.f, 0.f, 0.f, 0.f};
#pragma unroll
        for (int s = 0; s < NSPLIT; ++s) {
            const __bf16* pl = OpartT + ((size_t)(s * BATCH * HEADS + b * HEADS + h) * DIM_HEAD + d) * NQ
                               + q0 + qq;
            bf16x4 v4 = *(const bf16x4*)pl;
            acc[0] += (float)v4[0];
            acc[1] += (float)v4[1];
            acc[2] += (float)v4[2];
            acc[3] += (float)v4[3];
        }
        T[qq + 0][d] = acc[0] * INV[qq + 0];
        T[qq + 1][d] = acc[1] * INV[qq + 1];
        T[qq + 2][d] = acc[2] * INV[qq + 2];
        T[qq + 3][d] = acc[3] * INV[qq + 3];
    }
    __syncthreads();

    int q  = tid >> 2;
    int dc = (tid & 3) * 16;
    bf16x8 r0, r1;
#pragma unroll
    for (int j = 0; j < 8; ++j) {
        r0[j] = (__bf16)T[q][dc + j];
        r1[j] = (__bf16)T[q][dc + 8 + j];
    }
    __bf16* dst = aob + (size_t)(b * NQ + q0 + q) * QDIM + h * DIM_HEAD + dc;
    *(bf16x8*)dst       = r0;
    *(bf16x8*)(dst + 8) = r1;
}

// ---------------------------------------------------------------------------
// kernel_launch. Workspace map (MB) — cvt buffers GONE:
//   OpartT 0-16 (attn time) | qbuf 16-20 | kvbK 20-36 (K-only, ldc=512) |
//   vtb 36-52 | aob 52-56 | lbuf 56-57
// ---------------------------------------------------------------------------
extern "C" void kernel_launch(void* const* d_in, const int* in_sizes, int n_in,
                              void* d_out, int out_size, void* d_ws, size_t ws_size,
                              hipStream_t stream) {
    const float* x   = (const float*)d_in[0];
    const float* ctx = (const float*)d_in[1];
    const float* Wq  = (const float*)d_in[3];
    const float* Wkv = (const float*)d_in[4];
    const float* Wo  = (const float*)d_in[5];
    const float* bo  = (const float*)d_in[6];

    char* ws = (char*)d_ws;
    const size_t MB = 1ull << 20;
    __bf16* OpartT = (__bf16*)(ws + 0 * MB);
    __bf16* qbuf   = (__bf16*)(ws + 16 * MB);
    __bf16* kvbK   = (__bf16*)(ws + 20 * MB);
    __bf16* vtb    = (__bf16*)(ws + 36 * MB);
    __bf16* aob    = (__bf16*)(ws + 52 * MB);
    float*  lb     = (float*)(ws + 56 * MB);

    dim3 blk(256);

    // fused projections straight from fp32 inputs (cvt folded into staging):
    // kv (1024 works) + q (128 works), XCD swizzle, reg-staged dbuf
    proj_fused<<<dim3(1152), blk, 0, stream>>>(x, Wq, qbuf, ctx, Wkv, kvbK, vtb);

    // attention partials (K-split x4, KVBLK=64, 512-thread blocks, XCD grid)
    attn_mfma32<<<dim3(NQ / 256 * HEADS * BATCH * NSPLIT), dim3(512), 0, stream>>>(
        qbuf, kvbK, vtb, OpartT, lb);

    // combine splits -> aob [4096, 512] bf16
    attn_combine<<<dim3(NQ / 64, HEADS, BATCH), blk, 0, stream>>>(OpartT, lb, aob);

    // out = aob @ Wo^T + bo  [4096, 512] fp32 — XCD-chunked, reg-staged dbuf,
    // Wo converted fp32->bf16 in the staging path
    gemm_bt_64f<<<dim3(256), blk, 0, stream>>>(
        aob, Wo, bo, (float*)d_out, BATCH * NQ, QDIM, QDIM);
}

// Round 23
// 102.228 us; speedup vs baseline: 1.0494x; 1.0494x over previous
//
#include <hip/hip_runtime.h>
#include <hip/hip_bf16.h>
#include <math.h>

// Problem constants
#define HEADS    8
#define DIM_HEAD 64
#define QDIM     512
#define BATCH    4
#define NQ       1024
#define NKV      4096
#define NSPLIT   4
#define KEYS_PER_SPLIT (NKV / NSPLIT)   // 1024
#define NT (KEYS_PER_SPLIT / 64)        // 16 tiles per split

typedef float  f32x4  __attribute__((ext_vector_type(4)));
typedef float  f32x16 __attribute__((ext_vector_type(16)));
typedef __bf16 bf16x8 __attribute__((ext_vector_type(8)));
typedef __bf16 bf16x4 __attribute__((ext_vector_type(4)));

#define MFMA16(a, b, c) __builtin_amdgcn_mfma_f32_16x16x32_bf16((a), (b), (c), 0, 0, 0)
#define MFMA32(a, b, c) __builtin_amdgcn_mfma_f32_32x32x16_bf16((a), (b), (c), 0, 0, 0)

// Q-projection scale: (1/8) * log2(e)  [folds exp->exp2], softmax shift = -4
#define QSCALE 0.1803368801111204f
#define SSHIFT -4.0f

// ---------------------------------------------------------------------------
// Merged fp32 -> bf16 conversion for all 5 tensors (one launch).
// ---------------------------------------------------------------------------
__global__ __launch_bounds__(256) void cvt_all(
    const float* __restrict__ x,   const float* __restrict__ ctx,
    const float* __restrict__ wq,  const float* __restrict__ wkv,
    const float* __restrict__ wo,
    __bf16* __restrict__ xb,  __bf16* __restrict__ ctxb,
    __bf16* __restrict__ wqb, __bf16* __restrict__ wkvb,
    __bf16* __restrict__ wob)
{
    size_t i = (size_t)(blockIdx.x * 256 + threadIdx.x) * 8;
    const float* src; __bf16* dst; size_t off;
    if      (i <  2097152) { src = x;   dst = xb;   off = i; }
    else if (i < 10485760) { src = ctx; dst = ctxb; off = i - 2097152; }
    else if (i < 10747904) { src = wq;  dst = wqb;  off = i - 10485760; }
    else if (i < 11272192) { src = wkv; dst = wkvb; off = i - 10747904; }
    else                   { src = wo;  dst = wob;  off = i - 11272192; }
    float4 a = *(const float4*)(src + off);
    float4 b = *(const float4*)(src + off + 4);
    bf16x8 o;
    o[0] = (__bf16)a.x; o[1] = (__bf16)a.y; o[2] = (__bf16)a.z; o[3] = (__bf16)a.w;
    o[4] = (__bf16)b.x; o[5] = (__bf16)b.y; o[6] = (__bf16)b.z; o[7] = (__bf16)b.w;
    *(bf16x8*)(dst + off) = o;
}

// ---------------------------------------------------------------------------
// 128x128 GEMM tile body — REG-STAGED (r7/r12-proven loop): per K-step each
// thread issues 4 bf16x8 global loads EARLY (2 A rows, 2 B rows), computes
// the current LDS buffer (16 MFMA16), ds_writes the staged regs into the
// other buffer, ONE barrier. No global_load_lds drain on the critical path.
// KV_OUT: K-half row-major ldc=512 / V-half transposed.
// ---------------------------------------------------------------------------
template <bool KV_OUT>
__device__ __forceinline__ void gemm128_rs(
    const __bf16* __restrict__ A, const __bf16* __restrict__ W,
    __bf16* __restrict__ Cb, __bf16* __restrict__ Vt,
    __bf16* As, __bf16* Bs,           // each 2 * 128*32 bf16 (double buffer)
    int bm, int bn, int K, int N, float scale)
{
    const int tid = threadIdx.x;
    const int l   = tid & 63;
    const int wv  = tid >> 6;
    const int wr  = wv >> 1, wc = wv & 1;
    const int l15 = l & 15, lg = l >> 4;

    // staging geometry: rows r0 and r0+64, col c0 (bf16x8)
    const int r0 = tid >> 2, c0 = (tid & 3) * 8;
    const __bf16* ap = A + (size_t)(bm + r0) * K + c0;
    const __bf16* wp = W + (size_t)(bn + r0) * K + c0;
    const size_t rowK64 = (size_t)64 * K;
    const int sidx0 = r0 * 32 + c0;            // LDS elem offset, row r0
    const int sidx1 = (r0 + 64) * 32 + c0;     // row r0+64
    const int BUF = 128 * 32;                  // elems per buffer

    const f32x4 zero = {0.f, 0.f, 0.f, 0.f};
    f32x4 acc[4][4];
#pragma unroll
    for (int i = 0; i < 4; ++i)
#pragma unroll
        for (int j = 0; j < 4; ++j)
            acc[i][j] = zero;

    const int nk = K / 32;

    // prologue: stage K-step 0 into buffer 0
    {
        bf16x8 a0 = *(const bf16x8*)ap;
        bf16x8 a1 = *(const bf16x8*)(ap + rowK64);
        bf16x8 b0 = *(const bf16x8*)wp;
        bf16x8 b1 = *(const bf16x8*)(wp + rowK64);
        ap += 32; wp += 32;
        *(bf16x8*)&As[sidx0] = a0;
        *(bf16x8*)&As[sidx1] = a1;
        *(bf16x8*)&Bs[sidx0] = b0;
        *(bf16x8*)&Bs[sidx1] = b1;
    }
    __syncthreads();

    int cur = 0;
    for (int t = 0; t < nk - 1; ++t) {
        // issue next K-step's loads (latency hides under the MFMAs below)
        bf16x8 a0 = *(const bf16x8*)ap;
        bf16x8 a1 = *(const bf16x8*)(ap + rowK64);
        bf16x8 b0 = *(const bf16x8*)wp;
        bf16x8 b1 = *(const bf16x8*)(wp + rowK64);
        ap += 32; wp += 32;

        {   // compute from buf[cur]
            bf16x8 af[4], bfr[4];
#pragma unroll
            for (int i = 0; i < 4; ++i) {
                af[i]  = *(const bf16x8*)&As[cur * BUF + (wr * 64 + i * 16 + l15) * 32 + lg * 8];
                bfr[i] = *(const bf16x8*)&Bs[cur * BUF + (wc * 64 + i * 16 + l15) * 32 + lg * 8];
            }
#pragma unroll
            for (int i = 0; i < 4; ++i)
#pragma unroll
                for (int j = 0; j < 4; ++j)
                    acc[i][j] = MFMA16(af[i], bfr[j], acc[i][j]);
        }

        // write next K-step into the other buffer
        int nb = (cur ^ 1) * BUF;
        *(bf16x8*)&As[nb + sidx0] = a0;
        *(bf16x8*)&As[nb + sidx1] = a1;
        *(bf16x8*)&Bs[nb + sidx0] = b0;
        *(bf16x8*)&Bs[nb + sidx1] = b1;
        __syncthreads();
        cur ^= 1;
    }
    {   // final K-step
        bf16x8 af[4], bfr[4];
#pragma unroll
        for (int i = 0; i < 4; ++i) {
            af[i]  = *(const bf16x8*)&As[cur * BUF + (wr * 64 + i * 16 + l15) * 32 + lg * 8];
            bfr[i] = *(const bf16x8*)&Bs[cur * BUF + (wc * 64 + i * 16 + l15) * 32 + lg * 8];
        }
#pragma unroll
        for (int i = 0; i < 4; ++i)
#pragma unroll
            for (int j = 0; j < 4; ++j)
                acc[i][j] = MFMA16(af[i], bfr[j], acc[i][j]);
    }

    if (KV_OUT) {
        if (bn < QDIM) {
            // K half: row-major, ldc = QDIM (K-only buffer)
#pragma unroll
            for (int i = 0; i < 4; ++i) {
                int row0 = bm + wr * 64 + i * 16 + lg * 4;
#pragma unroll
                for (int j = 0; j < 4; ++j) {
                    int col = bn + wc * 64 + j * 16 + l15;
#pragma unroll
                    for (int r = 0; r < 4; ++r)
                        Cb[(size_t)(row0 + r) * QDIM + col] = (__bf16)(acc[i][j][r] * scale);
                }
            }
        } else {
            // V half: transposed store Vt[(b*H+h)*64+d][t..t+3]
#pragma unroll
            for (int i = 0; i < 4; ++i) {
                int row0 = bm + wr * 64 + i * 16 + lg * 4;   // global token row
                int bb = row0 >> 12;
                int tt = row0 & (NKV - 1);
#pragma unroll
                for (int j = 0; j < 4; ++j) {
                    int vcol = bn + wc * 64 + j * 16 + l15 - QDIM;
                    int hh = vcol >> 6, dd = vcol & 63;
                    bf16x4 o4;
#pragma unroll
                    for (int r = 0; r < 4; ++r) o4[r] = (__bf16)(acc[i][j][r] * scale);
                    *(bf16x4*)&Vt[((size_t)(bb * HEADS + hh) * DIM_HEAD + dd) * NKV + tt] = o4;
                }
            }
        }
    } else {
#pragma unroll
        for (int i = 0; i < 4; ++i) {
            int row0 = bm + wr * 64 + i * 16 + lg * 4;
#pragma unroll
            for (int j = 0; j < 4; ++j) {
                int col = bn + wc * 64 + j * 16 + l15;
#pragma unroll
                for (int r = 0; r < 4; ++r)
                    Cb[(size_t)(row0 + r) * N + col] = (__bf16)(acc[i][j][r] * scale);
            }
        }
    }
}

// ---------------------------------------------------------------------------
// Fused projections with XCD-chunked swizzle (1152 = 8 XCDs x 144 works):
// work = (bid%8)*144 + bid/8. kv works 0..1023 (8 blocks sharing an A-panel
// co-locate on one XCD); q works 1024..1151 fill the tail. Reg-staged body.
// ---------------------------------------------------------------------------
__global__ __launch_bounds__(256, 2) void proj_fused(
    const __bf16* __restrict__ xb,   const __bf16* __restrict__ Wqb,
    __bf16* __restrict__ qbuf,
    const __bf16* __restrict__ ctxb, const __bf16* __restrict__ Wkvb,
    __bf16* __restrict__ kvbK, __bf16* __restrict__ vtb)
{
    __shared__ __bf16 As[2 * 128 * 32];
    __shared__ __bf16 Bs[2 * 128 * 32];

    const int bid = (blockIdx.x & 7) * 144 + (blockIdx.x >> 3);   // bijective
    if (bid < 1024) {
        int bn = (bid & 7) * 128;
        int bm = (bid >> 3) * 128;
        gemm128_rs<true>(ctxb, Wkvb, kvbK, vtb, As, Bs, bm, bn, QDIM, 2 * QDIM, 1.0f);
    } else {
        int q  = bid - 1024;           // 0..127
        int bn = (q & 3) * 128;
        int bm = (q >> 2) * 128;
        gemm128_rs<false>(xb, Wqb, qbuf, nullptr, As, Bs, bm, bn, QDIM, QDIM, QSCALE);
    }
}

// ---------------------------------------------------------------------------
// bf16 MFMA GEMM, 128x64 tile, reg-staged dbuf — final projection (N=512).
// 1-D grid of 256 blocks with XCD-chunked swizzle (256 = 8 x 32).
// Per K-step per thread: 2 A-loads + 1 B-load (bf16x8), early-issued.
// ---------------------------------------------------------------------------
__global__ __launch_bounds__(256, 2) void gemm_bt_64f(
    const __bf16* __restrict__ A, const __bf16* __restrict__ W,
    const float* __restrict__ bias, float* __restrict__ Cf,
    int M, int N, int K)
{
    __shared__ __bf16 As[2 * 128 * 32];
    __shared__ __bf16 Bs[2 * 64 * 32];

    const int tid = threadIdx.x;
    const int l   = tid & 63;
    const int wv  = tid >> 6;
    const int wr  = wv >> 1, wc = wv & 1;
    const int l15 = l & 15, lg = l >> 4;
    const int bid = (blockIdx.x & 7) * 32 + (blockIdx.x >> 3);    // bijective
    const int bm  = (bid >> 3) * 128, bn = (bid & 7) * 64;

    const int r0 = tid >> 2, c0 = (tid & 3) * 8;
    const __bf16* ap = A + (size_t)(bm + r0) * K + c0;
    const __bf16* wp = W + (size_t)(bn + r0) * K + c0;   // rows 0..63 only
    const size_t rowK64 = (size_t)64 * K;
    const int sidx0 = r0 * 32 + c0;
    const int sidx1 = (r0 + 64) * 32 + c0;
    const int ABUF = 128 * 32, BBUF = 64 * 32;
    const bool bact = r0 < 64;                            // threads staging B

    const f32x4 zero = {0.f, 0.f, 0.f, 0.f};
    f32x4 acc[4][2];
#pragma unroll
    for (int i = 0; i < 4; ++i)
#pragma unroll
        for (int j = 0; j < 2; ++j)
            acc[i][j] = zero;

    const int nk = K / 32;

    {   // prologue
        bf16x8 a0 = *(const bf16x8*)ap;
        bf16x8 a1 = *(const bf16x8*)(ap + rowK64);
        bf16x8 b0;
        if (bact) b0 = *(const bf16x8*)wp;
        ap += 32; wp += 32;
        *(bf16x8*)&As[sidx0] = a0;
        *(bf16x8*)&As[sidx1] = a1;
        if (bact) *(bf16x8*)&Bs[sidx0] = b0;
    }
    __syncthreads();

    int cur = 0;
    for (int t = 0; t < nk - 1; ++t) {
        bf16x8 a0 = *(const bf16x8*)ap;
        bf16x8 a1 = *(const bf16x8*)(ap + rowK64);
        bf16x8 b0;
        if (bact) b0 = *(const bf16x8*)wp;
        ap += 32; wp += 32;

        {
            bf16x8 af[4], bfr[2];
#pragma unroll
            for (int i = 0; i < 4; ++i)
                af[i]  = *(const bf16x8*)&As[cur * ABUF + (wr * 64 + i * 16 + l15) * 32 + lg * 8];
#pragma unroll
            for (int j = 0; j < 2; ++j)
                bfr[j] = *(const bf16x8*)&Bs[cur * BBUF + (wc * 32 + j * 16 + l15) * 32 + lg * 8];
#pragma unroll
            for (int i = 0; i < 4; ++i)
#pragma unroll
                for (int j = 0; j < 2; ++j)
                    acc[i][j] = MFMA16(af[i], bfr[j], acc[i][j]);
        }

        *(bf16x8*)&As[(cur ^ 1) * ABUF + sidx0] = a0;
        *(bf16x8*)&As[(cur ^ 1) * ABUF + sidx1] = a1;
        if (bact) *(bf16x8*)&Bs[(cur ^ 1) * BBUF + sidx0] = b0;
        __syncthreads();
        cur ^= 1;
    }
    {
        bf16x8 af[4], bfr[2];
#pragma unroll
        for (int i = 0; i < 4; ++i)
            af[i]  = *(const bf16x8*)&As[cur * ABUF + (wr * 64 + i * 16 + l15) * 32 + lg * 8];
#pragma unroll
        for (int j = 0; j < 2; ++j)
            bfr[j] = *(const bf16x8*)&Bs[cur * BBUF + (wc * 32 + j * 16 + l15) * 32 + lg * 8];
#pragma unroll
        for (int i = 0; i < 4; ++i)
#pragma unroll
            for (int j = 0; j < 2; ++j)
                acc[i][j] = MFMA16(af[i], bfr[j], acc[i][j]);
    }

#pragma unroll
    for (int i = 0; i < 4; ++i) {
        int row0 = bm + wr * 64 + i * 16 + lg * 4;
#pragma unroll
        for (int j = 0; j < 2; ++j) {
            int col = bn + wc * 32 + j * 16 + l15;
            float bv = bias[col];
#pragma unroll
            for (int r = 0; r < 4; ++r)
                Cf[(size_t)(row0 + r) * N + col] = acc[i][j][r] + bv;
        }
    }
}

// ---------------------------------------------------------------------------
// Flash attention, 32x32x16 MFMA, swapped operands, K-split x4, static-shift
// softmax. r12-proven kernel (45.0 µs): KVBLK=64, 512-thread blocks (8 waves,
// 256 q-rows), double-buffered LDS, ONE barrier per tile, early-issue loads,
// shiftv C-operand, VALU lsum. 1-D XCD grid: bid%8 = h. UNCHANGED.
// ---------------------------------------------------------------------------
#define LSA 72

__device__ inline unsigned pkbf(float a, float b) {
    union { __bf16 h[2]; unsigned u; } r;
    r.h[0] = (__bf16)a; r.h[1] = (__bf16)b;
    return r.u;
}

__global__ __launch_bounds__(512, 4) void attn_mfma32(
    const __bf16* __restrict__ Q,      // [B*NQ, 512], pre-scaled by QSCALE
    const __bf16* __restrict__ Kb,     // [B*NKV, 512] K-only row-major
    const __bf16* __restrict__ VtG,    // [(B*H)*64][NKV] transposed V
    __bf16* __restrict__ OpartT,       // [NSPLIT*B*H][64 d][1024 q] bf16
    float* __restrict__ lbuf)          // [NSPLIT*B*H*NQ] f32 partial denoms
{
    __shared__ __bf16 Ks[2][64][LSA];
    __shared__ __bf16 Vs[2][64][LSA];  // Vs[buf][d][key]

    const int tid = threadIdx.x;
    const int w   = tid >> 6;          // 0..7
    const int l   = tid & 63;
    const int l31 = l & 31;
    const int hl  = l >> 5;

    // 1-D grid decomposition: bid = qbi*128 + (zz*8 + h); 512 blocks total
    const int bid   = blockIdx.x;
    const int inner = bid & 127;
    const int qbi   = bid >> 7;        // 0..3
    const int zz    = inner >> 3;      // 0..15
    const int h     = inner & 7;
    const int b     = zz & 3;
    const int split = zz >> 2;
    const int qb    = qbi * 256;       // 256 q-rows per block
    const int k_begin = split * KEYS_PER_SPLIT;

    // register constant: softmax shift as MFMA C-operand
    f32x16 shiftv;
#pragma unroll
    for (int r = 0; r < 16; ++r) shiftv[r] = SSHIFT;

    // Q fragments hoisted to registers
    const int qrow = qb + w * 32 + l31;
    const __bf16* qptr = Q + (size_t)(b * NQ + qrow) * QDIM + h * DIM_HEAD + hl * 8;
    bf16x8 qa[4];
#pragma unroll
    for (int m = 0; m < 4; ++m) qa[m] = *(const bf16x8*)(qptr + m * 16);

    // staging pointers: one bf16x8 of K and one of V per thread per tile
    const size_t kstep = (size_t)64 * QDIM;
    const int key0 = tid >> 3, ch = (tid & 7) * 8;       // K[key0][ch..ch+7]
    const __bf16* kp = Kb + (size_t)(b * NKV + k_begin + key0) * QDIM + h * DIM_HEAD + ch;
    const int vd = tid >> 3, vch = (tid & 7) * 8;        // Vt[vd][vch..vch+7]
    const __bf16* vp = VtG + ((size_t)(b * HEADS + h) * DIM_HEAD + vd) * NKV + k_begin + vch;

    f32x16 o0, o1;
#pragma unroll
    for (int r = 0; r < 16; ++r) { o0[r] = 0.f; o1[r] = 0.f; }
    float lsum = 0.0f;

    // per-tile compute from buffer `cur`
    auto compute_tile = [&](int cur) {
        f32x16 sf0, sf1;
        {
            bf16x8 kf0 = *(const bf16x8*)&Ks[cur][l31][hl * 8];
            bf16x8 kf1 = *(const bf16x8*)&Ks[cur][32 + l31][hl * 8];
            sf0 = MFMA32(kf0, qa[0], shiftv);
            sf1 = MFMA32(kf1, qa[0], shiftv);
        }
#pragma unroll
        for (int m = 1; m < 4; ++m) {
            bf16x8 kf0 = *(const bf16x8*)&Ks[cur][l31][m * 16 + hl * 8];
            bf16x8 kf1 = *(const bf16x8*)&Ks[cur][32 + l31][m * 16 + hl * 8];
            sf0 = MFMA32(kf0, qa[m], sf0);
            sf1 = MFMA32(kf1, qa[m], sf1);
        }

        unsigned pk0[8], pk1[8];
#pragma unroll
        for (int i = 0; i < 8; ++i) {
            float a0 = __builtin_amdgcn_exp2f(sf0[2 * i]);
            float a1 = __builtin_amdgcn_exp2f(sf0[2 * i + 1]);
            float b0 = __builtin_amdgcn_exp2f(sf1[2 * i]);
            float b1 = __builtin_amdgcn_exp2f(sf1[2 * i + 1]);
            lsum += (a0 + a1) + (b0 + b1);
            pk0[i] = pkbf(a0, a1);
            pk1[i] = pkbf(b0, b1);
        }

        // half-exchange via permlane32_swap: X.hi <-> Y.lo
        asm volatile("v_permlane32_swap_b32 %0, %1" : "+v"(pk0[0]), "+v"(pk0[2]));
        asm volatile("v_permlane32_swap_b32 %0, %1" : "+v"(pk0[1]), "+v"(pk0[3]));
        asm volatile("v_permlane32_swap_b32 %0, %1" : "+v"(pk0[4]), "+v"(pk0[6]));
        asm volatile("v_permlane32_swap_b32 %0, %1" : "+v"(pk0[5]), "+v"(pk0[7]));
        asm volatile("v_permlane32_swap_b32 %0, %1" : "+v"(pk1[0]), "+v"(pk1[2]));
        asm volatile("v_permlane32_swap_b32 %0, %1" : "+v"(pk1[1]), "+v"(pk1[3]));
        asm volatile("v_permlane32_swap_b32 %0, %1" : "+v"(pk1[4]), "+v"(pk1[6]));
        asm volatile("v_permlane32_swap_b32 %0, %1" : "+v"(pk1[5]), "+v"(pk1[7]));

        union { unsigned u[4]; bf16x8 v; } F0, F1, F2, F3;
        F0.u[0] = pk0[0]; F0.u[1] = pk0[1]; F0.u[2] = pk0[2]; F0.u[3] = pk0[3];
        F1.u[0] = pk0[4]; F1.u[1] = pk0[5]; F1.u[2] = pk0[6]; F1.u[3] = pk0[7];
        F2.u[0] = pk1[0]; F2.u[1] = pk1[1]; F2.u[2] = pk1[2]; F2.u[3] = pk1[3];
        F3.u[0] = pk1[4]; F3.u[1] = pk1[5]; F3.u[2] = pk1[6]; F3.u[3] = pk1[7];
        bf16x8 pf[4] = { F0.v, F1.v, F2.v, F3.v };

#pragma unroll
        for (int f = 0; f < 4; ++f) {
            bf16x8 v0 = *(const bf16x8*)&Vs[cur][l31][f * 16 + hl * 8];
            bf16x8 v1 = *(const bf16x8*)&Vs[cur][32 + l31][f * 16 + hl * 8];
            o0 = MFMA32(v0, pf[f], o0);
            o1 = MFMA32(v1, pf[f], o1);
        }
    };

    // prologue: stage tile 0
    {
        bf16x8 kr = *(const bf16x8*)kp;
        bf16x8 vr = *(const bf16x8*)vp;
        kp += kstep; vp += 64;
        *(bf16x8*)&Ks[0][key0][ch] = kr;
        *(bf16x8*)&Vs[0][vd][vch]  = vr;
    }
    __syncthreads();

    int cur = 0;
    for (int t = 0; t < NT - 1; ++t) {
        // issue next tile's loads (latency hidden under compute below)
        bf16x8 kr = *(const bf16x8*)kp;
        bf16x8 vr = *(const bf16x8*)vp;
        kp += kstep; vp += 64;

        compute_tile(cur);

        // write next tile into the other buffer (no pre-write barrier needed)
        *(bf16x8*)&Ks[cur ^ 1][key0][ch] = kr;
        *(bf16x8*)&Vs[cur ^ 1][vd][vch]  = vr;
        __syncthreads();
        cur ^= 1;
    }
    compute_tile(cur);

    // ---- epilogue ----
    float ltot = lsum + __shfl_xor(lsum, 32);
    const int S1 = BATCH * HEADS * NQ;
    int qidx = (b * HEADS + h) * NQ + qrow;
    if (l < 32) lbuf[(size_t)split * S1 + qidx] = ltot;

    __bf16* plane = OpartT + (size_t)(split * BATCH * HEADS + b * HEADS + h) * DIM_HEAD * NQ;
#pragma unroll
    for (int r = 0; r < 16; ++r) {
        int d = (r & 3) + 8 * (r >> 2) + 4 * hl;
        plane[(size_t)d * NQ + qrow]        = (__bf16)o0[r];
        plane[(size_t)(32 + d) * NQ + qrow] = (__bf16)o1[r];
    }
}

// ---------------------------------------------------------------------------
// Combine: out[q,d] = (sum_s O_s[d,q]) / (sum_s l_s[q]).
// ---------------------------------------------------------------------------
__global__ __launch_bounds__(256) void attn_combine(
    const __bf16* __restrict__ OpartT, const float* __restrict__ lbuf,
    __bf16* __restrict__ aob)
{
    __shared__ float T[64][65];
    __shared__ float INV[64];

    const int tid = threadIdx.x;
    const int q0  = blockIdx.x * 64;
    const int h   = blockIdx.y;
    const int b   = blockIdx.z;
    const int S1  = BATCH * HEADS * NQ;

    if (tid < 64) {
        int qidx = (b * HEADS + h) * NQ + q0 + tid;
        float den = 0.f;
#pragma unroll
        for (int s = 0; s < NSPLIT; ++s) den += lbuf[(size_t)s * S1 + qidx];
        INV[tid] = 1.0f / den;
    }
    __syncthreads();

    const int qq = (tid & 15) * 4;
    const int dr = tid >> 4;
#pragma unroll
    for (int dd = 0; dd < 4; ++dd) {
        int d = dr + dd * 16;
        f32x4 acc = {0.f, 0.f, 0.f, 0.f};
#pragma unroll
        for (int s = 0; s < NSPLIT; ++s) {
            const __bf16* pl = OpartT + ((size_t)(s * BATCH * HEADS + b * HEADS + h) * DIM_HEAD + d) * NQ
                               + q0 + qq;
            bf16x4 v4 = *(const bf16x4*)pl;
            acc[0] += (float)v4[0];
            acc[1] += (float)v4[1];
            acc[2] += (float)v4[2];
            acc[3] += (float)v4[3];
        }
        T[qq + 0][d] = acc[0] * INV[qq + 0];
        T[qq + 1][d] = acc[1] * INV[qq + 1];
        T[qq + 2][d] = acc[2] * INV[qq + 2];
        T[qq + 3][d] = acc[3] * INV[qq + 3];
    }
    __syncthreads();

    int q  = tid >> 2;
    int dc = (tid & 3) * 16;
    bf16x8 r0, r1;
#pragma unroll
    for (int j = 0; j < 8; ++j) {
        r0[j] = (__bf16)T[q][dc + j];
        r1[j] = (__bf16)T[q][dc + 8 + j];
    }
    __bf16* dst = aob + (size_t)(b * NQ + q0 + q) * QDIM + h * DIM_HEAD + dc;
    *(bf16x8*)dst       = r0;
    *(bf16x8*)(dst + 8) = r1;
}

// ---------------------------------------------------------------------------
// kernel_launch. Workspace map (MB):
//   proj-time: xb 0-4 | ctxb 4-20
//   attn-time: OpartT 0-16 (overlays dead xb/ctxb)
//   Wqb 20-20.5 | Wkvb 20.5-21.5 | Wob 21.5-22 | qbuf 22-26 |
//   kvbK 26-42 (K-only, ldc=512) | vtb 42-58 | aob 58-62 | lbuf 62-63
// ---------------------------------------------------------------------------
extern "C" void kernel_launch(void* const* d_in, const int* in_sizes, int n_in,
                              void* d_out, int out_size, void* d_ws, size_t ws_size,
                              hipStream_t stream) {
    const float* x   = (const float*)d_in[0];
    const float* ctx = (const float*)d_in[1];
    const float* Wq  = (const float*)d_in[3];
    const float* Wkv = (const float*)d_in[4];
    const float* Wo  = (const float*)d_in[5];
    const float* bo  = (const float*)d_in[6];

    char* ws = (char*)d_ws;
    const size_t MB = 1ull << 20;
    __bf16* xb     = (__bf16*)(ws + 0 * MB);
    __bf16* ctxb   = (__bf16*)(ws + 4 * MB);
    __bf16* OpartT = (__bf16*)(ws + 0 * MB);               // 16 MB, attn time
    __bf16* Wqb    = (__bf16*)(ws + 20 * MB);
    __bf16* Wkvb   = (__bf16*)(ws + 20 * MB + 512 * 1024);
    __bf16* Wob    = (__bf16*)(ws + 21 * MB + 512 * 1024);
    __bf16* qbuf   = (__bf16*)(ws + 22 * MB);
    __bf16* kvbK   = (__bf16*)(ws + 26 * MB);
    __bf16* vtb    = (__bf16*)(ws + 42 * MB);
    __bf16* aob    = (__bf16*)(ws + 58 * MB);
    float*  lb     = (float*)(ws + 62 * MB);

    dim3 blk(256);

    // all fp32->bf16 conversions in one launch
    cvt_all<<<dim3(5632), blk, 0, stream>>>(x, ctx, Wq, Wkv, Wo, xb, ctxb, Wqb, Wkvb, Wob);

    // fused projections: kv (1024 works) + q (128 works), XCD swizzle,
    // reg-staged early-issue dbuf (r7 lever)
    proj_fused<<<dim3(1152), blk, 0, stream>>>(xb, Wqb, qbuf, ctxb, Wkvb, kvbK, vtb);

    // attention partials (K-split x4, KVBLK=64, 512-thread blocks, XCD grid)
    attn_mfma32<<<dim3(NQ / 256 * HEADS * BATCH * NSPLIT), dim3(512), 0, stream>>>(
        qbuf, kvbK, vtb, OpartT, lb);

    // combine splits -> aob [4096, 512] bf16
    attn_combine<<<dim3(NQ / 64, HEADS, BATCH), blk, 0, stream>>>(OpartT, lb, aob);

    // out = aob @ Wo^T + bo  [4096, 512] fp32 — XCD-chunked, reg-staged dbuf
    gemm_bt_64f<<<dim3(256), blk, 0, stream>>>(
        aob, Wob, bo, (float*)d_out, BATCH * NQ, QDIM, QDIM);
}